// Round 5
// baseline (127.609 us; speedup 1.0000x reference)
//
#include <hip/hip_runtime.h>

#define NP  44
#define B   400000
#define B4  (B / 4)       // 100000 float4 groups per particle
#define BLK 256
#define CPT 8             // float4 chunks per thread (8 loads in flight)

typedef float v4f __attribute__((ext_vector_type(4)));   // clang-native vec4 (NT-builtin compatible)

// Bias-free 1->4->8->4->1 ReLU MLP with scalar input is positively homogeneous:
//   y(x) = gp*x  (x>=0),   gn*x  (x<0)  — exact, per particle.
__device__ __forceinline__ void collapse_weights(
    const float* __restrict__ p1, const float* __restrict__ p2,
    const float* __restrict__ p3, const float* __restrict__ p4,
    float& gp, float& gn)
{
    float w1p[4], w1n[4];
#pragma unroll
    for (int k = 0; k < 4; ++k) {
        float w = p1[k];
        w1p[k] = fmaxf(w, 0.0f);
        w1n[k] = fminf(w, 0.0f);
    }

    float d2p[8], d2n[8];
#pragma unroll
    for (int i = 0; i < 8; ++i) {
        float ap = 0.0f, an = 0.0f;
#pragma unroll
        for (int k = 0; k < 4; ++k) {
            float w = p2[i * 4 + k];
            ap = fmaf(w, w1p[k], ap);
            an = fmaf(w, w1n[k], an);
        }
        d2p[i] = fmaxf(ap, 0.0f);
        d2n[i] = fminf(an, 0.0f);   // relu(x*c) = x*min(c,0) when x<0
    }

    float f3p[4], f3n[4];
#pragma unroll
    for (int j = 0; j < 4; ++j) {
        float ap = 0.0f, an = 0.0f;
#pragma unroll
        for (int i = 0; i < 8; ++i) {
            float w = p3[j * 8 + i];
            ap = fmaf(w, d2p[i], ap);
            an = fmaf(w, d2n[i], an);
        }
        f3p[j] = fmaxf(ap, 0.0f);
        f3n[j] = fminf(an, 0.0f);
    }

    gp = 0.0f; gn = 0.0f;
#pragma unroll
    for (int j = 0; j < 4; ++j) {
        gp = fmaf(p4[j], f3p[j], gp);
        gn = fmaf(p4[j], f3n[j], gn);
    }
}

__device__ __forceinline__ v4f scale4(v4f v, float gp, float gn) {
    v4f r;
    r.x = v.x * (v.x >= 0.0f ? gp : gn);
    r.y = v.y * (v.y >= 0.0f ? gp : gn);
    r.z = v.z * (v.z >= 0.0f ? gp : gn);
    r.w = v.w * (v.w >= 0.0f ? gp : gn);
    return r;
}

__global__ __launch_bounds__(BLK) void collapsed_mlp_kernel(
    const float* __restrict__ X,    // (NP, 1, B)
    const float* __restrict__ W1,   // (NP, 4, 1)
    const float* __restrict__ W2,   // (NP, 8, 4)
    const float* __restrict__ W3,   // (NP, 4, 8)
    const float* __restrict__ W4,   // (NP, 1, 4)
    float* __restrict__ out)        // (NP, 1, B)
{
    const int l    = blockIdx.y;
    const int base = blockIdx.x * (BLK * CPT) + threadIdx.x;

    const v4f* Xp = (const v4f*)(X + (size_t)l * B);
    v4f*       Op = (v4f*)(out + (size_t)l * B);

    const bool full = (blockIdx.x + 1) * (BLK * CPT) <= B4;

    // Streaming loads first — 8 independent dwordx4 in flight while the
    // wave-uniform collapse math runs.
    v4f xv[CPT];
    if (full) {
#pragma unroll
        for (int c = 0; c < CPT; ++c) xv[c] = Xp[base + c * BLK];
    }

    float gp, gn;
    collapse_weights(W1 + l * 4, W2 + l * 32, W3 + l * 32, W4 + l * 4, gp, gn);

    if (full) {
#pragma unroll
        for (int c = 0; c < CPT; ++c) {
            // Nontemporal store: out is never re-read — keep L2/L3 for X.
            __builtin_nontemporal_store(scale4(xv[c], gp, gn), &Op[base + c * BLK]);
        }
    } else {
#pragma unroll
        for (int c = 0; c < CPT; ++c) {
            const int idx = base + c * BLK;
            if (idx < B4) {
                v4f v = Xp[idx];
                __builtin_nontemporal_store(scale4(v, gp, gn), &Op[idx]);
            }
        }
    }
}

extern "C" void kernel_launch(void* const* d_in, const int* in_sizes, int n_in,
                              void* d_out, int out_size, void* d_ws, size_t ws_size,
                              hipStream_t stream) {
    const float* X  = (const float*)d_in[0];
    const float* W1 = (const float*)d_in[1];
    const float* W2 = (const float*)d_in[2];
    const float* W3 = (const float*)d_in[3];
    const float* W4 = (const float*)d_in[4];
    float* out = (float*)d_out;

    dim3 grid((B4 + BLK * CPT - 1) / (BLK * CPT), NP);   // (49, 44)
    collapsed_mlp_kernel<<<grid, BLK, 0, stream>>>(X, W1, W2, W3, W4, out);
}